// Round 1
// baseline (939.377 us; speedup 1.0000x reference)
//
#include <hip/hip_runtime.h>

typedef __bf16 bf16x8 __attribute__((ext_vector_type(8)));
typedef float f32x4 __attribute__((ext_vector_type(4)));

__device__ __forceinline__ float bf2f(unsigned short u) {
  union { unsigned int i; float f; } v; v.i = ((unsigned int)u) << 16; return v.f;
}
__device__ __forceinline__ unsigned short f2bf(float f) {
  union { float f; unsigned int i; } v; v.f = f;
  unsigned int u = v.i;
  u += 0x7fffu + ((u >> 16) & 1u);
  return (unsigned short)(u >> 16);
}

// ---------------- fp32 -> bf16 convert ----------------
__global__ void f2b_kernel(const float* __restrict__ in,
                           unsigned short* __restrict__ out, int n4) {
  int i = blockIdx.x * 256 + threadIdx.x;
  if (i < n4) {
    float4 v = ((const float4*)in)[i];
    ushort4 o;
    o.x = f2bf(v.x); o.y = f2bf(v.y); o.z = f2bf(v.z); o.w = f2bf(v.w);
    ((ushort4*)out)[i] = o;
  }
}

// ---------------- async global->LDS 16B ----------------
__device__ __forceinline__ void async16(const void* g, void* s) {
  __builtin_amdgcn_global_load_lds(
      (const __attribute__((address_space(1))) unsigned int*)g,
      (__attribute__((address_space(3))) unsigned int*)s, 16, 0, 0);
}

// ---------------- bf16 GEMM, Bt = (N,K) row-major (i.e. C = A * Bt^T) ------
// 128x128 tile, BK=32, 4 waves (2x2), 16x16x32 MFMA. M%128==0, N%128==0,
// K%32==0 required. Epilogue: +bias, optional relu, bf16 or fp32 out.
template<int OUTF32, int RELU>
__global__ __launch_bounds__(256, 2)
void gemm_bt(const unsigned short* __restrict__ A,   // M x K bf16
             const unsigned short* __restrict__ Bt,  // N x K bf16
             void* __restrict__ Cv,                  // out, ld = ldC
             const float* __restrict__ bias,         // length N (fp32)
             int M, int N, int K, int ldC, int colOff)
{
  __shared__ unsigned short As[128 * 32];
  __shared__ unsigned short Bs[128 * 32];

  const int mblocks = M >> 7;
  const int tm = (int)blockIdx.x % mblocks;
  const int tn = (int)blockIdx.x / mblocks;
  const int t = threadIdx.x;
  const int w = t >> 6;
  const int l = t & 63;
  const int wr = w >> 1, wc = w & 1;
  const int lr = l & 15, kg = l >> 4;

  const unsigned short* Abase = A + (size_t)tm * 128 * K;
  const unsigned short* Bbase = Bt + (size_t)tn * 128 * K;

  // staging: 16B chunk c = issue*256 + t; row = c>>2, sub = (c&3)*8 elems
  const int c0 = t, c1 = 256 + t;
  const int r0 = c0 >> 2, s0 = (c0 & 3) * 8;
  const int r1 = c1 >> 2, s1 = (c1 & 3) * 8;
  unsigned short* AsD0 = As + (w * 512);
  unsigned short* AsD1 = As + (2048 + w * 512);
  unsigned short* BsD0 = Bs + (w * 512);
  unsigned short* BsD1 = Bs + (2048 + w * 512);

  const f32x4 zero4 = {0.f, 0.f, 0.f, 0.f};
  f32x4 acc[4][4];
  #pragma unroll
  for (int m = 0; m < 4; ++m)
    #pragma unroll
    for (int n = 0; n < 4; ++n) acc[m][n] = zero4;

  for (int kt = 0; kt < K; kt += 32) {
    async16(Abase + (size_t)r0 * K + kt + s0, AsD0);
    async16(Abase + (size_t)r1 * K + kt + s1, AsD1);
    async16(Bbase + (size_t)r0 * K + kt + s0, BsD0);
    async16(Bbase + (size_t)r1 * K + kt + s1, BsD1);
    __syncthreads();  // drains vmcnt before barrier
    bf16x8 af[4], bfv[4];
    #pragma unroll
    for (int m = 0; m < 4; ++m)
      af[m] = *(const bf16x8*)&As[(wr * 64 + m * 16 + lr) * 32 + kg * 8];
    #pragma unroll
    for (int n = 0; n < 4; ++n)
      bfv[n] = *(const bf16x8*)&Bs[(wc * 64 + n * 16 + lr) * 32 + kg * 8];
    #pragma unroll
    for (int m = 0; m < 4; ++m)
      #pragma unroll
      for (int n = 0; n < 4; ++n)
        acc[m][n] = __builtin_amdgcn_mfma_f32_16x16x32_bf16(af[m], bfv[n],
                                                            acc[m][n], 0, 0, 0);
    __syncthreads();
  }

  const int row0 = tm * 128 + wr * 64;
  const int colL0 = tn * 128 + wc * 64;
  #pragma unroll
  for (int n = 0; n < 4; ++n) {
    const int ccol = colL0 + n * 16 + lr;
    const float bv = bias[ccol];
    #pragma unroll
    for (int m = 0; m < 4; ++m) {
      #pragma unroll
      for (int r = 0; r < 4; ++r) {
        const int crow = row0 + m * 16 + kg * 4 + r;
        float v = acc[m][n][r] + bv;
        if (RELU) v = fmaxf(v, 0.f);
        if (OUTF32)
          ((float*)Cv)[(size_t)crow * ldC + colOff + ccol] = v;
        else
          ((unsigned short*)Cv)[(size_t)crow * ldC + colOff + ccol] = f2bf(v);
      }
    }
  }
}

// ---------------- sliding-window attention -------------------------------
// One block per (b, chunk n, head h). qkv: (36864, 1536) bf16 rows = b*192+s,
// cols [0,512)=Q [512,1024)=K [1024,1536)=V (head h at h*64).
// hbranch: K/V rows fetched transposed (row = ka*192 + b).
// ctx out: (36864, 512) bf16.
__global__ __launch_bounds__(256)
void attn_win(const unsigned short* __restrict__ qkv,
              unsigned short* __restrict__ ctx,
              const int hbranch)
{
  __shared__ float Qs[32][68];          // pre-scaled by 1/8
  __shared__ float Ks[96][68];
  __shared__ unsigned short Vs[96][68]; // bf16
  __shared__ float Ps[32][100];
  __shared__ float rsum[32];

  const int t = threadIdx.x;
  const int bid = blockIdx.x;
  const int h = bid & 7;
  const int n = (bid >> 3) % 6;
  const int b = bid / 48;
  const int cbase = h * 64;

  // load Q (32x64): 512 quads
  #pragma unroll
  for (int i = 0; i < 2; ++i) {
    int e = i * 256 + t;
    int r = e >> 4, d4 = (e & 15) * 4;
    int row = b * 192 + n * 32 + r;
    ushort4 q4 = *(const ushort4*)&qkv[(size_t)row * 1536 + cbase + d4];
    float4 qf;
    qf.x = bf2f(q4.x) * 0.125f; qf.y = bf2f(q4.y) * 0.125f;
    qf.z = bf2f(q4.z) * 0.125f; qf.w = bf2f(q4.w) * 0.125f;
    *(float4*)&Qs[r][d4] = qf;
  }
  // load K,V (96x64): 1536 quads each
  #pragma unroll
  for (int i = 0; i < 6; ++i) {
    int e = i * 256 + t;
    int kk = e >> 4, d4 = (e & 15) * 4;
    int ka = (n - 1) * 32 + kk;
    float4 kf = {0.f, 0.f, 0.f, 0.f};
    ushort4 v4; v4.x = 0; v4.y = 0; v4.z = 0; v4.w = 0;
    if (ka >= 0 && ka < 192) {
      int row = hbranch ? (ka * 192 + b) : (b * 192 + ka);
      ushort4 k4 = *(const ushort4*)&qkv[(size_t)row * 1536 + 512 + cbase + d4];
      v4 = *(const ushort4*)&qkv[(size_t)row * 1536 + 1024 + cbase + d4];
      kf.x = bf2f(k4.x); kf.y = bf2f(k4.y); kf.z = bf2f(k4.z); kf.w = bf2f(k4.w);
    }
    *(float4*)&Ks[kk][d4] = kf;
    *(ushort4*)&Vs[kk][d4] = v4;
  }
  __syncthreads();

  // scores: 32x96, 12 per thread
  #pragma unroll
  for (int i = 0; i < 12; ++i) {
    int e = i * 256 + t;
    int q = e / 96, kk = e - q * 96;
    const float4* Qr = (const float4*)&Qs[q][0];
    const float4* Kr = (const float4*)&Ks[kk][0];
    float s = 0.f;
    #pragma unroll
    for (int j = 0; j < 16; ++j) {
      float4 a = Qr[j], k = Kr[j];
      s += a.x * k.x + a.y * k.y + a.z * k.z + a.w * k.w;
    }
    int ka = (n - 1) * 32 + kk;
    bool valid = (kk >= q) && (kk <= q + 64) && (ka >= 0) && (ka < 192);
    Ps[q][kk] = valid ? s : -1e30f;
  }
  __syncthreads();

  // softmax: 8 threads per row
  {
    const int r = t >> 3, g = t & 7;
    float mx = -1e30f;
    #pragma unroll
    for (int i = 0; i < 12; ++i) mx = fmaxf(mx, Ps[r][g + 8 * i]);
    mx = fmaxf(mx, __shfl_xor(mx, 1));
    mx = fmaxf(mx, __shfl_xor(mx, 2));
    mx = fmaxf(mx, __shfl_xor(mx, 4));
    float sum = 0.f;
    #pragma unroll
    for (int i = 0; i < 12; ++i) {
      float ev = __expf(Ps[r][g + 8 * i] - mx);
      Ps[r][g + 8 * i] = ev;
      sum += ev;
    }
    sum += __shfl_xor(sum, 1);
    sum += __shfl_xor(sum, 2);
    sum += __shfl_xor(sum, 4);
    if (g == 0) rsum[r] = 1.f / sum;
  }
  __syncthreads();

  // PV: 32x64 out, float4 per thread iter
  #pragma unroll
  for (int i = 0; i < 2; ++i) {
    int e = i * 256 + t;
    int q = e >> 4, d4 = (e & 15) * 4;
    float4 o = {0.f, 0.f, 0.f, 0.f};
    #pragma unroll 8
    for (int kk = 0; kk < 96; ++kk) {
      float p = Ps[q][kk];
      ushort4 v4 = *(const ushort4*)&Vs[kk][d4];
      o.x += p * bf2f(v4.x);
      o.y += p * bf2f(v4.y);
      o.z += p * bf2f(v4.z);
      o.w += p * bf2f(v4.w);
    }
    float rs = rsum[q];
    int row = b * 192 + n * 32 + q;
    ushort4 pk;
    pk.x = f2bf(o.x * rs); pk.y = f2bf(o.y * rs);
    pk.z = f2bf(o.z * rs); pk.w = f2bf(o.w * rs);
    *(ushort4*)&ctx[(size_t)row * 512 + cbase + d4] = pk;
  }
}

// ---------------- launch ----------------
extern "C" void kernel_launch(void* const* d_in, const int* in_sizes, int n_in,
                              void* d_out, int out_size, void* d_ws, size_t ws_size,
                              hipStream_t stream) {
  const float* x       = (const float*)d_in[0];
  const float* h_in_w  = (const float*)d_in[1];
  const float* h_in_b  = (const float*)d_in[2];
  const float* h_out_w = (const float*)d_in[3];
  const float* h_out_b = (const float*)d_in[4];
  const float* v_in_w  = (const float*)d_in[5];
  const float* v_in_b  = (const float*)d_in[6];
  const float* v_out_w = (const float*)d_in[7];
  const float* v_out_b = (const float*)d_in[8];
  const float* w1      = (const float*)d_in[9];
  const float* b1      = (const float*)d_in[10];
  const float* w2      = (const float*)d_in[11];
  const float* b2      = (const float*)d_in[12];

  // workspace layout (bytes)
  const size_t XB   = 0;                       // 36864*512*2   = 37,748,736
  const size_t WV   = 37748736;                // 1536*512*2
  const size_t WH   = 39321600;
  const size_t WHO  = 40894464;                // 512*512*2
  const size_t WVO  = 41418752;
  const size_t W1B  = 41943040;                // 512*1024*2
  const size_t W2B  = 42991616;
  const size_t CTXV = 43515904;                // 36864*512*2
  const size_t CTXH = 81264640;
  const size_t QKV  = 119013376;               // 36864*1536*2 = 113,246,208
  const size_t NEED = 232259584;               // 232 MB
  if (ws_size < NEED) return;                  // fail loudly, don't corrupt

  char* ws = (char*)d_ws;
  unsigned short* xb   = (unsigned short*)(ws + XB);
  unsigned short* wv   = (unsigned short*)(ws + WV);
  unsigned short* wh   = (unsigned short*)(ws + WH);
  unsigned short* who  = (unsigned short*)(ws + WHO);
  unsigned short* wvo  = (unsigned short*)(ws + WVO);
  unsigned short* w1b  = (unsigned short*)(ws + W1B);
  unsigned short* w2b  = (unsigned short*)(ws + W2B);
  unsigned short* ctxv = (unsigned short*)(ws + CTXV);
  unsigned short* ctxh = (unsigned short*)(ws + CTXH);
  unsigned short* qkv  = (unsigned short*)(ws + QKV);
  unsigned short* comb = (unsigned short*)(ws + QKV);   // alias (after attn)
  unsigned short* hid  = (unsigned short*)(ws + CTXV);  // alias (after proj)

  auto cv = [&](const float* src, unsigned short* dst, int nelem) {
    int n4 = nelem >> 2;
    f2b_kernel<<<(n4 + 255) / 256, 256, 0, stream>>>(src, dst, n4);
  };
  cv(x, xb, 36864 * 512);
  cv(v_in_w, wv, 1536 * 512);
  cv(h_in_w, wh, 1536 * 512);
  cv(h_out_w, who, 512 * 512);
  cv(v_out_w, wvo, 512 * 512);
  cv(w1, w1b, 512 * 1024);
  cv(w2, w2b, 512 * 512);

  const int M = 36864;
  // v branch
  gemm_bt<0, 0><<<288 * 12, 256, 0, stream>>>(xb, wv, qkv, v_in_b, M, 1536, 512, 1536, 0);
  attn_win<<<9216, 256, 0, stream>>>(qkv, ctxv, 0);
  // h branch (reuses qkv buffer)
  gemm_bt<0, 0><<<288 * 12, 256, 0, stream>>>(xb, wh, qkv, h_in_b, M, 1536, 512, 1536, 0);
  attn_win<<<9216, 256, 0, stream>>>(qkv, ctxh, 1);
  // output projections -> combined (B,S,1024): [h_out | v_out]
  gemm_bt<0, 0><<<288 * 4, 256, 0, stream>>>(ctxh, who, comb, h_out_b, M, 512, 512, 1024, 0);
  gemm_bt<0, 0><<<288 * 4, 256, 0, stream>>>(ctxv, wvo, comb, v_out_b, M, 512, 512, 1024, 512);
  // MLP
  gemm_bt<0, 1><<<288 * 4, 256, 0, stream>>>(comb, w1b, hid, b1, M, 512, 1024, 512, 0);
  gemm_bt<1, 0><<<288 * 4, 256, 0, stream>>>(hid, w2b, d_out, b2, M, 512, 512, 512, 0);
}

// Round 2
// 587.543 us; speedup vs baseline: 1.5988x; 1.5988x over previous
//
#include <hip/hip_runtime.h>

typedef __bf16 bf16x8 __attribute__((ext_vector_type(8)));
typedef __bf16 bf16x4 __attribute__((ext_vector_type(4)));
typedef float f32x4 __attribute__((ext_vector_type(4)));

__device__ __forceinline__ float bf2f(unsigned short u) {
  union { unsigned int i; float f; } v; v.i = ((unsigned int)u) << 16; return v.f;
}
__device__ __forceinline__ unsigned short f2bf(float f) {
  union { float f; unsigned int i; } v; v.f = f;
  unsigned int u = v.i;
  u += 0x7fffu + ((u >> 16) & 1u);
  return (unsigned short)(u >> 16);
}

// ---------------- fp32 -> bf16 convert ----------------
__global__ void f2b_kernel(const float* __restrict__ in,
                           unsigned short* __restrict__ out, int n4) {
  int i = blockIdx.x * 256 + threadIdx.x;
  if (i < n4) {
    float4 v = ((const float4*)in)[i];
    ushort4 o;
    o.x = f2bf(v.x); o.y = f2bf(v.y); o.z = f2bf(v.z); o.w = f2bf(v.w);
    ((ushort4*)out)[i] = o;
  }
}

// ---------------- async global->LDS 16B ----------------
__device__ __forceinline__ void async16(const void* g, void* s) {
  __builtin_amdgcn_global_load_lds(
      (const __attribute__((address_space(1))) unsigned int*)g,
      (__attribute__((address_space(3))) unsigned int*)s, 16, 0, 0);
}

// ---------------- bf16 GEMM, Bt = (N,K) row-major (C = A * Bt^T) ----------
// 128x128 tile, BK=32, 4 waves (2x2), 16x16x32 MFMA.
// VT=1: scatter epilogue into transposed V buffer vt[b1][h][d][s1] where
//   HBR=0: b1=r/192, s1=r%192 (v-branch)   HBR=1: b1=r%192, s1=r/192 (h)
template<int OUTF32, int RELU, int VT, int HBR>
__global__ __launch_bounds__(256, 2)
void gemm_bt(const unsigned short* __restrict__ A,   // M x K bf16
             const unsigned short* __restrict__ Bt,  // N x K bf16
             void* __restrict__ Cv,                  // out
             const float* __restrict__ bias,         // length N (fp32)
             int M, int N, int K, int ldC, int colOff)
{
  __shared__ unsigned short As[128 * 32];
  __shared__ unsigned short Bs[128 * 32];

  const int mblocks = M >> 7;
  const int tm = (int)blockIdx.x % mblocks;
  const int tn = (int)blockIdx.x / mblocks;
  const int t = threadIdx.x;
  const int w = t >> 6;
  const int l = t & 63;
  const int wr = w >> 1, wc = w & 1;
  const int lr = l & 15, kg = l >> 4;

  const unsigned short* Abase = A + (size_t)tm * 128 * K;
  const unsigned short* Bbase = Bt + (size_t)tn * 128 * K;

  const int c0 = t, c1 = 256 + t;
  const int r0 = c0 >> 2, s0 = (c0 & 3) * 8;
  const int r1 = c1 >> 2, s1 = (c1 & 3) * 8;
  unsigned short* AsD0 = As + (w * 512);
  unsigned short* AsD1 = As + (2048 + w * 512);
  unsigned short* BsD0 = Bs + (w * 512);
  unsigned short* BsD1 = Bs + (2048 + w * 512);

  const f32x4 zero4 = {0.f, 0.f, 0.f, 0.f};
  f32x4 acc[4][4];
  #pragma unroll
  for (int m = 0; m < 4; ++m)
    #pragma unroll
    for (int n = 0; n < 4; ++n) acc[m][n] = zero4;

  for (int kt = 0; kt < K; kt += 32) {
    async16(Abase + (size_t)r0 * K + kt + s0, AsD0);
    async16(Abase + (size_t)r1 * K + kt + s1, AsD1);
    async16(Bbase + (size_t)r0 * K + kt + s0, BsD0);
    async16(Bbase + (size_t)r1 * K + kt + s1, BsD1);
    __syncthreads();
    bf16x8 af[4], bfv[4];
    #pragma unroll
    for (int m = 0; m < 4; ++m)
      af[m] = *(const bf16x8*)&As[(wr * 64 + m * 16 + lr) * 32 + kg * 8];
    #pragma unroll
    for (int n = 0; n < 4; ++n)
      bfv[n] = *(const bf16x8*)&Bs[(wc * 64 + n * 16 + lr) * 32 + kg * 8];
    #pragma unroll
    for (int m = 0; m < 4; ++m)
      #pragma unroll
      for (int n = 0; n < 4; ++n)
        acc[m][n] = __builtin_amdgcn_mfma_f32_16x16x32_bf16(af[m], bfv[n],
                                                            acc[m][n], 0, 0, 0);
    __syncthreads();
  }

  const int row0 = tm * 128 + wr * 64;
  const int colL0 = tn * 128 + wc * 64;

  if (VT) {
    unsigned short* vtout = (unsigned short*)Cv;
    #pragma unroll
    for (int n = 0; n < 4; ++n) {
      const int ccol = colL0 + n * 16 + lr;      // 0..511
      const float bv = bias[ccol];
      const int hh = ccol >> 6, dd = ccol & 63;
      const size_t hb = ((size_t)hh * 64 + dd) * 192;
      #pragma unroll
      for (int m = 0; m < 4; ++m) {
        const int rb = row0 + m * 16 + kg * 4;
        if (!HBR) {
          const int b1 = rb / 192, sq = rb % 192;  // 4 consecutive s
          ushort4 pk;
          pk.x = f2bf(acc[m][n][0] + bv);
          pk.y = f2bf(acc[m][n][1] + bv);
          pk.z = f2bf(acc[m][n][2] + bv);
          pk.w = f2bf(acc[m][n][3] + bv);
          *(ushort4*)&vtout[(size_t)b1 * 98304 + hb + sq] = pk;
        } else {
          #pragma unroll
          for (int r = 0; r < 4; ++r) {
            const int rr = rb + r;
            const int b1 = rr % 192, sq = rr / 192;
            vtout[(size_t)b1 * 98304 + hb + sq] = f2bf(acc[m][n][r] + bv);
          }
        }
      }
    }
    return;
  }

  #pragma unroll
  for (int n = 0; n < 4; ++n) {
    const int ccol = colL0 + n * 16 + lr;
    const float bv = bias[ccol];
    #pragma unroll
    for (int m = 0; m < 4; ++m) {
      #pragma unroll
      for (int r = 0; r < 4; ++r) {
        const int crow = row0 + m * 16 + kg * 4 + r;
        float v = acc[m][n][r] + bv;
        if (RELU) v = fmaxf(v, 0.f);
        if (OUTF32)
          ((float*)Cv)[(size_t)crow * ldC + colOff + ccol] = v;
        else
          ((unsigned short*)Cv)[(size_t)crow * ldC + colOff + ccol] = f2bf(v);
      }
    }
  }
}

// ---------------- MFMA sliding-window attention ---------------------------
// Block = (b, n, head-group of 4). Wave w handles head hg*4+w independently.
// qk: (36864, 1024) bf16 [Q | K].  vt: [b1][h][64][192] bf16 (V transposed,
// branch-aware mapping baked in by the V-GEMM).  ctx out: (36864,512) bf16.
// S^T = mfma(K, Q): col=q (lane&15), row=k (kg*4+r, +16/mt-tile).
__global__ __launch_bounds__(256)
void attn_mfma(const unsigned short* __restrict__ qk,
               const unsigned short* __restrict__ vt,
               unsigned short* __restrict__ ctx, int hbranch)
{
  __shared__ unsigned short P_lds[4][32 * 104];
  __shared__ float rinv[4][32];

  const int t = threadIdx.x;
  const int w = t >> 6, l = t & 63;
  const int lr = l & 15, kg = l >> 4;
  const int bid = blockIdx.x;
  const int hg = bid & 1;
  const int n = (bid >> 1) % 6;
  const int b = bid / 12;
  const int h = hg * 4 + w;
  const int kabase = (n - 1) * 32;

  // ---- Q fragments (B-operand: lane holds Q[ct*16+lr][ks*32+kg*8..+8]) ----
  bf16x8 qf[2][2];
  #pragma unroll
  for (int ct = 0; ct < 2; ++ct)
    #pragma unroll
    for (int ks = 0; ks < 2; ++ks)
      qf[ct][ks] = *(const bf16x8*)&qk[(size_t)(b * 192 + n * 32 + ct * 16 + lr) * 1024
                                       + h * 64 + ks * 32 + kg * 8];

  // ---- QK^T -> S^T (6 k-tiles x 2 q-tiles) ----
  const f32x4 z4 = {0.f, 0.f, 0.f, 0.f};
  f32x4 sacc[6][2];
  #pragma unroll
  for (int mt = 0; mt < 6; ++mt) { sacc[mt][0] = z4; sacc[mt][1] = z4; }

  #pragma unroll
  for (int mt = 0; mt < 6; ++mt) {
    int ka = kabase + mt * 16 + lr;
    ka = ka < 0 ? 0 : (ka > 191 ? 191 : ka);                 // clamp; masked later
    const size_t row = hbranch ? (size_t)ka * 192 + b : (size_t)b * 192 + ka;
    #pragma unroll
    for (int ks = 0; ks < 2; ++ks) {
      bf16x8 kf = *(const bf16x8*)&qk[row * 1024 + 512 + h * 64 + ks * 32 + kg * 8];
      #pragma unroll
      for (int ct = 0; ct < 2; ++ct)
        sacc[mt][ct] = __builtin_amdgcn_mfma_f32_16x16x32_bf16(kf, qf[ct][ks],
                                                               sacc[mt][ct], 0, 0, 0);
    }
  }

  // ---- issue V^T fragments early (latency hides under softmax VALU) ----
  bf16x8 vf[4][3];
  #pragma unroll
  for (int dt = 0; dt < 4; ++dt)
    #pragma unroll
    for (int t2 = 0; t2 < 3; ++t2) {
      int ka0 = kabase + t2 * 32 + kg * 8;
      if (ka0 < 0 || ka0 > 184) ka0 = 0;                     // fully-masked run
      vf[dt][t2] = *(const bf16x8*)&vt[((size_t)(b * 8 + h) * 64 + dt * 16 + lr) * 192 + ka0];
    }

  // ---- mask + softmax (in-register; reduce across kg via shfl_xor 16,32) --
  unsigned short* Pw = &P_lds[w][0];
  #pragma unroll
  for (int ct = 0; ct < 2; ++ct) {
    const int q = ct * 16 + lr;
    float mx = -1e30f;
    #pragma unroll
    for (int mt = 0; mt < 6; ++mt)
      #pragma unroll
      for (int rr = 0; rr < 4; ++rr) {
        const int kk = mt * 16 + kg * 4 + rr;
        const int ka = kabase + kk;
        const bool valid = (kk >= q) && (kk <= q + 64) && (ka >= 0) && (ka < 192);
        const float s = valid ? sacc[mt][ct][rr] : -1e30f;
        sacc[mt][ct][rr] = s;
        mx = fmaxf(mx, s);
      }
    mx = fmaxf(mx, __shfl_xor(mx, 16));
    mx = fmaxf(mx, __shfl_xor(mx, 32));
    float sum = 0.f;
    #pragma unroll
    for (int mt = 0; mt < 6; ++mt) {
      bf16x4 pk;
      #pragma unroll
      for (int rr = 0; rr < 4; ++rr) {
        // scale 1/sqrt(64)=0.125 folded with log2(e): exp(0.125*(s-mx))
        const float e = exp2f((sacc[mt][ct][rr] - mx) * 0.1803368801111137f);
        sum += e;
        pk[rr] = (__bf16)e;
      }
      *(bf16x4*)&Pw[q * 104 + mt * 16 + kg * 4] = pk;
    }
    sum += __shfl_xor(sum, 16);
    sum += __shfl_xor(sum, 32);
    if (kg == 0) rinv[w][q] = 1.0f / sum;
  }

  // ---- PV: O = P(32x96) * V(96x64), A-frags from wave-private LDS ----
  f32x4 oacc[2][4];
  #pragma unroll
  for (int mq = 0; mq < 2; ++mq)
    #pragma unroll
    for (int dt = 0; dt < 4; ++dt) oacc[mq][dt] = z4;

  #pragma unroll
  for (int t2 = 0; t2 < 3; ++t2)
    #pragma unroll
    for (int mq = 0; mq < 2; ++mq) {
      bf16x8 pa = *(const bf16x8*)&Pw[(mq * 16 + lr) * 104 + t2 * 32 + kg * 8];
      #pragma unroll
      for (int dt = 0; dt < 4; ++dt)
        oacc[mq][dt] = __builtin_amdgcn_mfma_f32_16x16x32_bf16(pa, vf[dt][t2],
                                                               oacc[mq][dt], 0, 0, 0);
    }

  // ---- epilogue: scale by 1/rowsum, store bf16 ----
  #pragma unroll
  for (int mq = 0; mq < 2; ++mq)
    #pragma unroll
    for (int rr = 0; rr < 4; ++rr) {
      const int q = mq * 16 + kg * 4 + rr;
      const float rv = rinv[w][q];
      const size_t row = (size_t)(b * 192 + n * 32 + q) * 512 + h * 64;
      #pragma unroll
      for (int dt = 0; dt < 4; ++dt)
        ctx[row + dt * 16 + lr] = f2bf(oacc[mq][dt][rr] * rv);
    }
}

// ---------------- launch ----------------
extern "C" void kernel_launch(void* const* d_in, const int* in_sizes, int n_in,
                              void* d_out, int out_size, void* d_ws, size_t ws_size,
                              hipStream_t stream) {
  const float* x       = (const float*)d_in[0];
  const float* h_in_w  = (const float*)d_in[1];
  const float* h_in_b  = (const float*)d_in[2];
  const float* h_out_w = (const float*)d_in[3];
  const float* h_out_b = (const float*)d_in[4];
  const float* v_in_w  = (const float*)d_in[5];
  const float* v_in_b  = (const float*)d_in[6];
  const float* v_out_w = (const float*)d_in[7];
  const float* v_out_b = (const float*)d_in[8];
  const float* w1      = (const float*)d_in[9];
  const float* b1      = (const float*)d_in[10];
  const float* w2      = (const float*)d_in[11];
  const float* b2      = (const float*)d_in[12];

  // workspace layout (bytes)
  const size_t XB   = 0;                 // 36864*512*2
  const size_t WV   = 37748736;          // 1536*512*2
  const size_t WH   = 39321600;
  const size_t WHO  = 40894464;          // 512*512*2
  const size_t WVO  = 41418752;
  const size_t W1B  = 41943040;          // 512*1024*2
  const size_t W2B  = 42991616;
  const size_t CTXV = 43515904;          // 36864*512*2
  const size_t CTXH = 81264640;
  const size_t QKO  = 119013376;         // 36864*1024*2 = 75,497,472
  const size_t VTO  = 194510848;         // 36864*512*2
  const size_t NEED = 232259584;
  if (ws_size < NEED) return;

  char* ws = (char*)d_ws;
  unsigned short* xb   = (unsigned short*)(ws + XB);
  unsigned short* wv   = (unsigned short*)(ws + WV);
  unsigned short* wh   = (unsigned short*)(ws + WH);
  unsigned short* who  = (unsigned short*)(ws + WHO);
  unsigned short* wvo  = (unsigned short*)(ws + WVO);
  unsigned short* w1b  = (unsigned short*)(ws + W1B);
  unsigned short* w2b  = (unsigned short*)(ws + W2B);
  unsigned short* ctxv = (unsigned short*)(ws + CTXV);
  unsigned short* ctxh = (unsigned short*)(ws + CTXH);
  unsigned short* qko  = (unsigned short*)(ws + QKO);
  unsigned short* vto  = (unsigned short*)(ws + VTO);
  unsigned short* comb = (unsigned short*)(ws + QKO);   // alias (after attn_h)
  unsigned short* hid  = (unsigned short*)(ws + CTXV);  // alias (after proj)

  auto cv = [&](const float* src, unsigned short* dst, int nelem) {
    int n4 = nelem >> 2;
    f2b_kernel<<<(n4 + 255) / 256, 256, 0, stream>>>(src, dst, n4);
  };
  cv(x, xb, 36864 * 512);
  cv(v_in_w, wv, 1536 * 512);
  cv(h_in_w, wh, 1536 * 512);
  cv(h_out_w, who, 512 * 512);
  cv(v_out_w, wvo, 512 * 512);
  cv(w1, w1b, 512 * 1024);
  cv(w2, w2b, 512 * 512);

  const int M = 36864;
  // ---- v branch: QK projection + V projection (transposed epilogue) ----
  gemm_bt<0, 0, 0, 0><<<288 * 8, 256, 0, stream>>>(xb, wv, qko, v_in_b, M, 1024, 512, 1024, 0);
  gemm_bt<0, 0, 1, 0><<<288 * 4, 256, 0, stream>>>(xb, wv + 1024 * 512, vto, v_in_b + 1024, M, 512, 512, 0, 0);
  attn_mfma<<<192 * 6 * 2, 256, 0, stream>>>(qko, vto, ctxv, 0);
  // ---- h branch (reuses qk/vt buffers) ----
  gemm_bt<0, 0, 0, 0><<<288 * 8, 256, 0, stream>>>(xb, wh, qko, h_in_b, M, 1024, 512, 1024, 0);
  gemm_bt<0, 0, 1, 1><<<288 * 4, 256, 0, stream>>>(xb, wh + 1024 * 512, vto, h_in_b + 1024, M, 512, 512, 0, 0);
  attn_mfma<<<192 * 6 * 2, 256, 0, stream>>>(qko, vto, ctxh, 1);
  // ---- output projections -> combined (B,S,1024) = [h_out | v_out] ----
  gemm_bt<0, 0, 0, 0><<<288 * 4, 256, 0, stream>>>(ctxh, who, comb, h_out_b, M, 512, 512, 1024, 0);
  gemm_bt<0, 0, 0, 0><<<288 * 4, 256, 0, stream>>>(ctxv, wvo, comb, v_out_b, M, 512, 512, 1024, 512);
  // ---- MLP ----
  gemm_bt<0, 1, 0, 0><<<288 * 4, 256, 0, stream>>>(comb, w1b, hid, b1, M, 512, 1024, 512, 0);
  gemm_bt<1, 0, 0, 0><<<288 * 4, 256, 0, stream>>>(hid, w2b, d_out, b2, M, 512, 512, 512, 0);
}

// Round 3
// 535.715 us; speedup vs baseline: 1.7535x; 1.0967x over previous
//
#include <hip/hip_runtime.h>

typedef __bf16 bf16x8 __attribute__((ext_vector_type(8)));
typedef __bf16 bf16x4 __attribute__((ext_vector_type(4)));
typedef float f32x4 __attribute__((ext_vector_type(4)));

__device__ __forceinline__ float bf2f(unsigned short u) {
  union { unsigned int i; float f; } v; v.i = ((unsigned int)u) << 16; return v.f;
}
__device__ __forceinline__ unsigned short f2bf(float f) {
  union { float f; unsigned int i; } v; v.f = f;
  unsigned int u = v.i;
  u += 0x7fffu + ((u >> 16) & 1u);
  return (unsigned short)(u >> 16);
}

// ---------------- fp32 -> bf16 convert ----------------
__global__ void f2b_kernel(const float* __restrict__ in,
                           unsigned short* __restrict__ out, int n4) {
  int i = blockIdx.x * 256 + threadIdx.x;
  if (i < n4) {
    float4 v = ((const float4*)in)[i];
    ushort4 o;
    o.x = f2bf(v.x); o.y = f2bf(v.y); o.z = f2bf(v.z); o.w = f2bf(v.w);
    ((ushort4*)out)[i] = o;
  }
}

// ---- fp32 -> bf16 convert + (b,s) row transpose: xt[s*192+b] = x[b*192+s] --
// Row-granular: both sides contiguous 512-elem rows -> fully coalesced.
__global__ void f2bt_kernel(const float* __restrict__ x,
                            unsigned short* __restrict__ xt) {
  const int t = threadIdx.x;
  const int half = t >> 7, idx = t & 127;
  const int ro = blockIdx.x * 2 + half;          // out row = s*192+b
  const int s = ro / 192, b = ro - s * 192;
  const int ri = b * 192 + s;
  float4 v = *(const float4*)&x[(size_t)ri * 512 + idx * 4];
  ushort4 o;
  o.x = f2bf(v.x); o.y = f2bf(v.y); o.z = f2bf(v.z); o.w = f2bf(v.w);
  *(ushort4*)&xt[(size_t)ro * 512 + idx * 4] = o;
}

// ---------------- async global->LDS 16B ----------------
__device__ __forceinline__ void async16(const void* g, void* s) {
  __builtin_amdgcn_global_load_lds(
      (const __attribute__((address_space(1))) unsigned int*)g,
      (__attribute__((address_space(3))) unsigned int*)s, 16, 0, 0);
}

// ---------------- bf16 GEMM, Bt = (N,K) row-major (C = A * Bt^T) ----------
// 128x128 tile, BK=32, 4 waves (2x2), 16x16x32 MFMA.
// MODE 0: C[M][ldC], bias indexed by column (+colOff), OUTF32/RELU options.
// MODE 1: batched V^T: grid = batches*8, sub: tm=sub&3 (M=512), tn=sub>>1&1
//   covers cols tn*64..tn*64+127 of N=192 (middle 64 written twice, benign).
//   A = weights (512xK), Bt = xsrc + (batch*192 + tn*64)*K.
//   C = vt + batch*98304, row-major [512][192], bias indexed by ROW.
template<int OUTF32, int RELU, int MODE>
__global__ __launch_bounds__(256, 2)
void gemm_bt(const unsigned short* __restrict__ A,   // M x K bf16
             const unsigned short* __restrict__ Bt,  // N x K bf16
             void* __restrict__ Cv,                  // out
             const float* __restrict__ bias,         // fp32
             int M, int N, int K, int ldC, int colOff)
{
  __shared__ unsigned short As[128 * 32];
  __shared__ unsigned short Bs[128 * 32];

  int tm, tn, batch = 0;
  if (MODE == 1) {
    const int bid = blockIdx.x;
    batch = bid >> 3;
    const int sub = bid & 7;
    tm = sub & 3;
    tn = sub >> 2;        // 0..1
  } else {
    const int mblocks = M >> 7;
    tm = (int)blockIdx.x % mblocks;
    tn = (int)blockIdx.x / mblocks;
  }
  const int t = threadIdx.x;
  const int w = t >> 6;
  const int l = t & 63;
  const int wr = w >> 1, wc = w & 1;
  const int lr = l & 15, kg = l >> 4;

  const unsigned short* Abase = A + (size_t)tm * 128 * K;
  const unsigned short* Bbase = (MODE == 1)
      ? Bt + ((size_t)batch * 192 + tn * 64) * K
      : Bt + (size_t)tn * 128 * K;

  const int c0 = t, c1 = 256 + t;
  const int r0 = c0 >> 2, s0 = (c0 & 3) * 8;
  const int r1 = c1 >> 2, s1 = (c1 & 3) * 8;
  unsigned short* AsD0 = As + (w * 512);
  unsigned short* AsD1 = As + (2048 + w * 512);
  unsigned short* BsD0 = Bs + (w * 512);
  unsigned short* BsD1 = Bs + (2048 + w * 512);

  const f32x4 zero4 = {0.f, 0.f, 0.f, 0.f};
  f32x4 acc[4][4];
  #pragma unroll
  for (int m = 0; m < 4; ++m)
    #pragma unroll
    for (int n = 0; n < 4; ++n) acc[m][n] = zero4;

  for (int kt = 0; kt < K; kt += 32) {
    async16(Abase + (size_t)r0 * K + kt + s0, AsD0);
    async16(Abase + (size_t)r1 * K + kt + s1, AsD1);
    async16(Bbase + (size_t)r0 * K + kt + s0, BsD0);
    async16(Bbase + (size_t)r1 * K + kt + s1, BsD1);
    __syncthreads();
    bf16x8 af[4], bfv[4];
    #pragma unroll
    for (int m = 0; m < 4; ++m)
      af[m] = *(const bf16x8*)&As[(wr * 64 + m * 16 + lr) * 32 + kg * 8];
    #pragma unroll
    for (int n = 0; n < 4; ++n)
      bfv[n] = *(const bf16x8*)&Bs[(wc * 64 + n * 16 + lr) * 32 + kg * 8];
    #pragma unroll
    for (int m = 0; m < 4; ++m)
      #pragma unroll
      for (int n = 0; n < 4; ++n)
        acc[m][n] = __builtin_amdgcn_mfma_f32_16x16x32_bf16(af[m], bfv[n],
                                                            acc[m][n], 0, 0, 0);
    __syncthreads();
  }

  const int row0 = tm * 128 + wr * 64;
  const int colL0 = (MODE == 1) ? (tn * 64 + wc * 64) : (tn * 128 + wc * 64);

  if (MODE == 1) {
    // C row-major [512][192]; rows = hd (bias rows), cols = s. Coalesced:
    // lanes lr write 16 consecutive ushorts per (m,n,rr).
    unsigned short* Cw = (unsigned short*)Cv + (size_t)batch * 98304;
    #pragma unroll
    for (int m = 0; m < 4; ++m) {
      const int rowb = row0 + m * 16 + kg * 4;
      const float4 bv4 = *(const float4*)&bias[rowb];
      #pragma unroll
      for (int rr = 0; rr < 4; ++rr) {
        const float bv = ((const float*)&bv4)[rr];
        const size_t rbase = (size_t)(rowb + rr) * 192;
        #pragma unroll
        for (int n = 0; n < 4; ++n) {
          const int j = colL0 + n * 16 + lr;
          Cw[rbase + j] = f2bf(acc[m][n][rr] + bv);
        }
      }
    }
    return;
  }

  #pragma unroll
  for (int n = 0; n < 4; ++n) {
    const int ccol = colL0 + n * 16 + lr;
    const float bv = bias[ccol];
    #pragma unroll
    for (int m = 0; m < 4; ++m) {
      #pragma unroll
      for (int r = 0; r < 4; ++r) {
        const int crow = row0 + m * 16 + kg * 4 + r;
        float v = acc[m][n][r] + bv;
        if (RELU) v = fmaxf(v, 0.f);
        if (OUTF32)
          ((float*)Cv)[(size_t)crow * ldC + colOff + ccol] = v;
        else
          ((unsigned short*)Cv)[(size_t)crow * ldC + colOff + ccol] = f2bf(v);
      }
    }
  }
}

// ---------------- MFMA sliding-window attention ---------------------------
// Block = (b, n, head-group of 4). Wave w handles head hg*4+w independently.
// qk: (36864, 1024) bf16 [Q | K].  vt: [b1][h][64][192] bf16.
// ctx out: (36864,512) bf16.  S^T = mfma(K, Q): col=q, row=k.
__global__ __launch_bounds__(256)
void attn_mfma(const unsigned short* __restrict__ qk,
               const unsigned short* __restrict__ vt,
               unsigned short* __restrict__ ctx, int hbranch)
{
  __shared__ unsigned short P_lds[4][32 * 104];
  __shared__ float rinv[4][32];

  const int t = threadIdx.x;
  const int w = t >> 6, l = t & 63;
  const int lr = l & 15, kg = l >> 4;
  const int bid = blockIdx.x;
  const int hg = bid & 1;
  const int n = (bid >> 1) % 6;
  const int b = bid / 12;
  const int h = hg * 4 + w;
  const int kabase = (n - 1) * 32;

  bf16x8 qf[2][2];
  #pragma unroll
  for (int ct = 0; ct < 2; ++ct)
    #pragma unroll
    for (int ks = 0; ks < 2; ++ks)
      qf[ct][ks] = *(const bf16x8*)&qk[(size_t)(b * 192 + n * 32 + ct * 16 + lr) * 1024
                                       + h * 64 + ks * 32 + kg * 8];

  const f32x4 z4 = {0.f, 0.f, 0.f, 0.f};
  f32x4 sacc[6][2];
  #pragma unroll
  for (int mt = 0; mt < 6; ++mt) { sacc[mt][0] = z4; sacc[mt][1] = z4; }

  #pragma unroll
  for (int mt = 0; mt < 6; ++mt) {
    int ka = kabase + mt * 16 + lr;
    ka = ka < 0 ? 0 : (ka > 191 ? 191 : ka);
    const size_t row = hbranch ? (size_t)ka * 192 + b : (size_t)b * 192 + ka;
    #pragma unroll
    for (int ks = 0; ks < 2; ++ks) {
      bf16x8 kf = *(const bf16x8*)&qk[row * 1024 + 512 + h * 64 + ks * 32 + kg * 8];
      #pragma unroll
      for (int ct = 0; ct < 2; ++ct)
        sacc[mt][ct] = __builtin_amdgcn_mfma_f32_16x16x32_bf16(kf, qf[ct][ks],
                                                               sacc[mt][ct], 0, 0, 0);
    }
  }

  bf16x8 vf[4][3];
  #pragma unroll
  for (int dt = 0; dt < 4; ++dt)
    #pragma unroll
    for (int t2 = 0; t2 < 3; ++t2) {
      int ka0 = kabase + t2 * 32 + kg * 8;
      if (ka0 < 0 || ka0 > 184) ka0 = 0;
      vf[dt][t2] = *(const bf16x8*)&vt[((size_t)(b * 8 + h) * 64 + dt * 16 + lr) * 192 + ka0];
    }

  unsigned short* Pw = &P_lds[w][0];
  #pragma unroll
  for (int ct = 0; ct < 2; ++ct) {
    const int q = ct * 16 + lr;
    float mx = -1e30f;
    #pragma unroll
    for (int mt = 0; mt < 6; ++mt)
      #pragma unroll
      for (int rr = 0; rr < 4; ++rr) {
        const int kk = mt * 16 + kg * 4 + rr;
        const int ka = kabase + kk;
        const bool valid = (kk >= q) && (kk <= q + 64) && (ka >= 0) && (ka < 192);
        const float s = valid ? sacc[mt][ct][rr] : -1e30f;
        sacc[mt][ct][rr] = s;
        mx = fmaxf(mx, s);
      }
    mx = fmaxf(mx, __shfl_xor(mx, 16));
    mx = fmaxf(mx, __shfl_xor(mx, 32));
    float sum = 0.f;
    #pragma unroll
    for (int mt = 0; mt < 6; ++mt) {
      bf16x4 pk;
      #pragma unroll
      for (int rr = 0; rr < 4; ++rr) {
        const float e = exp2f((sacc[mt][ct][rr] - mx) * 0.1803368801111137f);
        sum += e;
        pk[rr] = (__bf16)e;
      }
      *(bf16x4*)&Pw[q * 104 + mt * 16 + kg * 4] = pk;
    }
    sum += __shfl_xor(sum, 16);
    sum += __shfl_xor(sum, 32);
    if (kg == 0) rinv[w][q] = 1.0f / sum;
  }

  f32x4 oacc[2][4];
  #pragma unroll
  for (int mq = 0; mq < 2; ++mq)
    #pragma unroll
    for (int dt = 0; dt < 4; ++dt) oacc[mq][dt] = z4;

  #pragma unroll
  for (int t2 = 0; t2 < 3; ++t2)
    #pragma unroll
    for (int mq = 0; mq < 2; ++mq) {
      bf16x8 pa = *(const bf16x8*)&Pw[(mq * 16 + lr) * 104 + t2 * 32 + kg * 8];
      #pragma unroll
      for (int dt = 0; dt < 4; ++dt)
        oacc[mq][dt] = __builtin_amdgcn_mfma_f32_16x16x32_bf16(pa, vf[dt][t2],
                                                               oacc[mq][dt], 0, 0, 0);
    }

  #pragma unroll
  for (int mq = 0; mq < 2; ++mq)
    #pragma unroll
    for (int rr = 0; rr < 4; ++rr) {
      const int q = mq * 16 + kg * 4 + rr;
      const float rv = rinv[w][q];
      const size_t row = (size_t)(b * 192 + n * 32 + q) * 512 + h * 64;
      #pragma unroll
      for (int dt = 0; dt < 4; ++dt)
        ctx[row + dt * 16 + lr] = f2bf(oacc[mq][dt][rr] * rv);
    }
}

// ---------------- launch ----------------
extern "C" void kernel_launch(void* const* d_in, const int* in_sizes, int n_in,
                              void* d_out, int out_size, void* d_ws, size_t ws_size,
                              hipStream_t stream) {
  const float* x       = (const float*)d_in[0];
  const float* h_in_w  = (const float*)d_in[1];
  const float* h_in_b  = (const float*)d_in[2];
  const float* h_out_w = (const float*)d_in[3];
  const float* h_out_b = (const float*)d_in[4];
  const float* v_in_w  = (const float*)d_in[5];
  const float* v_in_b  = (const float*)d_in[6];
  const float* v_out_w = (const float*)d_in[7];
  const float* v_out_b = (const float*)d_in[8];
  const float* w1      = (const float*)d_in[9];
  const float* b1      = (const float*)d_in[10];
  const float* w2      = (const float*)d_in[11];
  const float* b2      = (const float*)d_in[12];

  // workspace layout (bytes)
  const size_t XB   = 0;                 // 36864*512*2
  const size_t WV   = 37748736;          // 1536*512*2
  const size_t WH   = 39321600;
  const size_t WHO  = 40894464;          // 512*512*2
  const size_t WVO  = 41418752;
  const size_t W1B  = 41943040;          // 512*1024*2
  const size_t W2B  = 42991616;
  const size_t CTXV = 43515904;          // 36864*512*2
  const size_t CTXH = 81264640;          // 36864*512*2 (xt aliases here)
  const size_t QKO  = 119013376;         // 36864*1024*2
  const size_t VTO  = 194510848;         // 36864*512*2
  const size_t NEED = 232259584;
  if (ws_size < NEED) return;

  char* ws = (char*)d_ws;
  unsigned short* xb   = (unsigned short*)(ws + XB);
  unsigned short* wv   = (unsigned short*)(ws + WV);
  unsigned short* wh   = (unsigned short*)(ws + WH);
  unsigned short* who  = (unsigned short*)(ws + WHO);
  unsigned short* wvo  = (unsigned short*)(ws + WVO);
  unsigned short* w1b  = (unsigned short*)(ws + W1B);
  unsigned short* w2b  = (unsigned short*)(ws + W2B);
  unsigned short* ctxv = (unsigned short*)(ws + CTXV);
  unsigned short* ctxh = (unsigned short*)(ws + CTXH);
  unsigned short* xt   = (unsigned short*)(ws + CTXH);  // alias: dead before ctxh written
  unsigned short* qko  = (unsigned short*)(ws + QKO);
  unsigned short* vto  = (unsigned short*)(ws + VTO);
  unsigned short* comb = (unsigned short*)(ws + QKO);   // alias (after attn_h)
  unsigned short* hid  = (unsigned short*)(ws + CTXV);  // alias (after proj)

  auto cv = [&](const float* src, unsigned short* dst, int nelem) {
    int n4 = nelem >> 2;
    f2b_kernel<<<(n4 + 255) / 256, 256, 0, stream>>>(src, dst, n4);
  };
  cv(x, xb, 36864 * 512);
  f2bt_kernel<<<36864 / 2, 256, 0, stream>>>(x, xt);
  cv(v_in_w, wv, 1536 * 512);
  cv(h_in_w, wh, 1536 * 512);
  cv(h_out_w, who, 512 * 512);
  cv(v_out_w, wvo, 512 * 512);
  cv(w1, w1b, 512 * 1024);
  cv(w2, w2b, 512 * 512);

  const int M = 36864;
  // ---- v branch: QK projection + batched V^T GEMM ----
  gemm_bt<0, 0, 0><<<288 * 8, 256, 0, stream>>>(xb, wv, qko, v_in_b, M, 1024, 512, 1024, 0);
  gemm_bt<0, 0, 1><<<192 * 8, 256, 0, stream>>>(wv + 1024 * 512, xb, vto, v_in_b + 1024, 512, 192, 512, 192, 0);
  attn_mfma<<<192 * 6 * 2, 256, 0, stream>>>(qko, vto, ctxv, 0);
  // ---- h branch: xt-based V^T GEMM (vt_h[b][h][d][ka] = Wv_h . xt[b*192+ka]) ----
  gemm_bt<0, 0, 0><<<288 * 8, 256, 0, stream>>>(xb, wh, qko, h_in_b, M, 1024, 512, 1024, 0);
  gemm_bt<0, 0, 1><<<192 * 8, 256, 0, stream>>>(wh + 1024 * 512, xt, vto, h_in_b + 1024, 512, 192, 512, 192, 0);
  attn_mfma<<<192 * 6 * 2, 256, 0, stream>>>(qko, vto, ctxh, 1);
  // ---- output projections -> combined (B,S,1024) = [h_out | v_out] ----
  gemm_bt<0, 0, 0><<<288 * 4, 256, 0, stream>>>(ctxh, who, comb, h_out_b, M, 512, 512, 1024, 0);
  gemm_bt<0, 0, 0><<<288 * 4, 256, 0, stream>>>(ctxv, wvo, comb, v_out_b, M, 512, 512, 1024, 512);
  // ---- MLP ----
  gemm_bt<0, 1, 0><<<288 * 4, 256, 0, stream>>>(comb, w1b, hid, b1, M, 512, 1024, 512, 0);
  gemm_bt<1, 0, 0><<<288 * 4, 256, 0, stream>>>(hid, w2b, d_out, b2, M, 512, 512, 512, 0);
}

// Round 4
// 482.083 us; speedup vs baseline: 1.9486x; 1.1112x over previous
//
#include <hip/hip_runtime.h>

typedef __bf16 bf16x8 __attribute__((ext_vector_type(8)));
typedef __bf16 bf16x4 __attribute__((ext_vector_type(4)));
typedef float f32x4 __attribute__((ext_vector_type(4)));

__device__ __forceinline__ float bf2f(unsigned short u) {
  union { unsigned int i; float f; } v; v.i = ((unsigned int)u) << 16; return v.f;
}
__device__ __forceinline__ unsigned short f2bf(float f) {
  union { float f; unsigned int i; } v; v.f = f;
  unsigned int u = v.i;
  u += 0x7fffu + ((u >> 16) & 1u);
  return (unsigned short)(u >> 16);
}

// ---------------- fused convert: x (dual), flat weights, transposed who/wvo
__global__ void cvt_all(const float* __restrict__ x,
                        const float* __restrict__ wv, const float* __restrict__ wh,
                        const float* __restrict__ w1, const float* __restrict__ w2,
                        const float* __restrict__ who, const float* __restrict__ wvo,
                        unsigned short* __restrict__ xb, unsigned short* __restrict__ xt,
                        unsigned short* __restrict__ wvb, unsigned short* __restrict__ whb,
                        unsigned short* __restrict__ w1b, unsigned short* __restrict__ w2b,
                        unsigned short* __restrict__ whoT, unsigned short* __restrict__ wvoT)
{
  const int bid = blockIdx.x;
  const int t = threadIdx.x;
  if (bid < 18432) {
    // x: one read -> xb (identity) + xt (row-permuted transpose)
    const int ro = bid * 2 + (t >> 7);           // xt row = s*192+b
    const int idx = t & 127;
    const int s = ro / 192, b = ro - s * 192;
    const int ri = b * 192 + s;                  // x/xb row
    float4 v = *(const float4*)&x[(size_t)ri * 512 + idx * 4];
    ushort4 o;
    o.x = f2bf(v.x); o.y = f2bf(v.y); o.z = f2bf(v.z); o.w = f2bf(v.w);
    *(ushort4*)&xb[(size_t)ri * 512 + idx * 4] = o;
    *(ushort4*)&xt[(size_t)ro * 512 + idx * 4] = o;
  } else if (bid < 20736) {
    // flat weight converts (segment boundaries are 256-quad aligned)
    int q = (bid - 18432) * 256 + t;
    const float* src; unsigned short* dst;
    if (q < 196608)      { src = wv;  dst = wvb; }
    else if (q < 393216) { src = wh;  dst = whb; q -= 196608; }
    else if (q < 524288) { src = w1;  dst = w1b; q -= 393216; }
    else                 { src = w2;  dst = w2b; q -= 524288; }
    float4 v = ((const float4*)src)[q];
    ushort4 o;
    o.x = f2bf(v.x); o.y = f2bf(v.y); o.z = f2bf(v.z); o.w = f2bf(v.w);
    ((ushort4*)dst)[q] = o;
  } else {
    // transposed convert: dst[j][i] = src[i][j]  (512x512)
    const int tb = bid - 20736;
    const float* src = (tb < 256) ? who : wvo;
    unsigned short* dst = (tb < 256) ? whoT : wvoT;
    const int j = (tb & 255) * 2 + (t >> 7);
    const int i0 = (t & 127) * 4;
    ushort4 o;
    o.x = f2bf(src[(size_t)(i0 + 0) * 512 + j]);
    o.y = f2bf(src[(size_t)(i0 + 1) * 512 + j]);
    o.z = f2bf(src[(size_t)(i0 + 2) * 512 + j]);
    o.w = f2bf(src[(size_t)(i0 + 3) * 512 + j]);
    *(ushort4*)&dst[(size_t)j * 512 + i0] = o;
  }
}

// ---------------- fused MLP1 bias: bf = b1 + W1a.h_out_b + W1b.v_out_b ----
__global__ void fuse_bias(const float* __restrict__ b1,
                          const float* __restrict__ hob,
                          const float* __restrict__ vob,
                          const float* __restrict__ w1,
                          float* __restrict__ bf)
{
  const int o = blockIdx.x * 256 + threadIdx.x;
  if (o < 512) {
    float s = b1[o];
    const float* row = w1 + (size_t)o * 1024;
    for (int m = 0; m < 512; ++m) s += row[m] * hob[m];
    for (int m = 0; m < 512; ++m) s += row[512 + m] * vob[m];
    bf[o] = s;
  }
}

// ---------------- async global->LDS 16B ----------------
__device__ __forceinline__ void async16(const void* g, void* s) {
  __builtin_amdgcn_global_load_lds(
      (const __attribute__((address_space(1))) unsigned int*)g,
      (__attribute__((address_space(3))) unsigned int*)s, 16, 0, 0);
}

// ---------------- bf16 GEMM, Bt = (N,K) row-major (C = A * Bt^T) ----------
// 128x128 tile, BK=32, 4 waves (2x2), 16x16x32 MFMA, double-buffered LDS:
// next tile's global_load_lds issued BEFORE current tile's compute; one
// __syncthreads per K-step (its vmcnt(0) lands after compute has run).
// MODE 0: C[M][ldC] at colOff. MODE 1: batched V^T (grid=batches*8,
//   tm=sub&3 over M=512, tn=sub>>2 covers cols tn*64..+127 of N=192;
//   middle 64 written twice with identical values). Bias by ROW in MODE 1.
template<int OUTF32, int RELU, int MODE, int ADDB>
__global__ __launch_bounds__(256, 2)
void gemm_bt(const unsigned short* __restrict__ A,
             const unsigned short* __restrict__ Bt,
             void* __restrict__ Cv,
             const float* __restrict__ bias,
             int M, int N, int K, int lda, int ldb, int ldC, int colOff)
{
  __shared__ unsigned short As[2][4096];
  __shared__ unsigned short Bs[2][4096];

  int tm, tn, batch = 0;
  if (MODE == 1) {
    batch = blockIdx.x >> 3;
    const int sub = blockIdx.x & 7;
    tm = sub & 3;
    tn = sub >> 2;
  } else {
    const int mb = M >> 7;
    tm = (int)blockIdx.x % mb;
    tn = (int)blockIdx.x / mb;
  }
  const int t = threadIdx.x;
  const int w = t >> 6, l = t & 63;
  const int wr = w >> 1, wc = w & 1;
  const int lr = l & 15, kg = l >> 4;

  const unsigned short* Abase = A + (size_t)tm * 128 * lda;
  const unsigned short* Bbase = (MODE == 1)
      ? Bt + ((size_t)batch * 192 + tn * 64) * ldb
      : Bt + (size_t)tn * 128 * ldb;

  const int r0 = t >> 2, s0 = (t & 3) * 8;
  const size_t ga0 = (size_t)r0 * lda + s0;
  const size_t ga1 = (size_t)(64 + r0) * lda + s0;
  const size_t gb0 = (size_t)r0 * ldb + s0;
  const size_t gb1 = (size_t)(64 + r0) * ldb + s0;
  const int ldsoff = w * 512;

  const f32x4 zero4 = {0.f, 0.f, 0.f, 0.f};
  f32x4 acc[4][4];
  #pragma unroll
  for (int m = 0; m < 4; ++m)
    #pragma unroll
    for (int n = 0; n < 4; ++n) acc[m][n] = zero4;

  const int nk = K >> 5;
  // prologue: stage tile 0 into buffer 0
  async16(Abase + ga0, &As[0][ldsoff]);
  async16(Abase + ga1, &As[0][2048 + ldsoff]);
  async16(Bbase + gb0, &Bs[0][ldsoff]);
  async16(Bbase + gb1, &Bs[0][2048 + ldsoff]);
  __syncthreads();

  for (int it = 0; it < nk; ++it) {
    const int cur = it & 1;
    if (it + 1 < nk) {
      const int kt = (it + 1) << 5;
      async16(Abase + ga0 + kt, &As[cur ^ 1][ldsoff]);
      async16(Abase + ga1 + kt, &As[cur ^ 1][2048 + ldsoff]);
      async16(Bbase + gb0 + kt, &Bs[cur ^ 1][ldsoff]);
      async16(Bbase + gb1 + kt, &Bs[cur ^ 1][2048 + ldsoff]);
    }
    bf16x8 af[4], bfv[4];
    #pragma unroll
    for (int m = 0; m < 4; ++m)
      af[m] = *(const bf16x8*)&As[cur][(wr * 64 + m * 16 + lr) * 32 + kg * 8];
    #pragma unroll
    for (int n = 0; n < 4; ++n)
      bfv[n] = *(const bf16x8*)&Bs[cur][(wc * 64 + n * 16 + lr) * 32 + kg * 8];
    #pragma unroll
    for (int m = 0; m < 4; ++m)
      #pragma unroll
      for (int n = 0; n < 4; ++n)
        acc[m][n] = __builtin_amdgcn_mfma_f32_16x16x32_bf16(af[m], bfv[n],
                                                            acc[m][n], 0, 0, 0);
    __syncthreads();   // drains this iter's prefetch (had compute to hide)
  }

  const int row0 = tm * 128 + wr * 64;
  const int colL0 = (MODE == 1) ? (tn * 64 + wc * 64) : (tn * 128 + wc * 64);

  if (MODE == 1) {
    unsigned short* Cw = (unsigned short*)Cv + (size_t)batch * 98304;
    #pragma unroll
    for (int m = 0; m < 4; ++m) {
      const int rowb = row0 + m * 16 + kg * 4;
      float4 bv4 = {0.f, 0.f, 0.f, 0.f};
      if (ADDB) bv4 = *(const float4*)&bias[rowb];
      #pragma unroll
      for (int rr = 0; rr < 4; ++rr) {
        const float bv = ((const float*)&bv4)[rr];
        const size_t rbase = (size_t)(rowb + rr) * 192;
        #pragma unroll
        for (int n = 0; n < 4; ++n) {
          const int j = colL0 + n * 16 + lr;
          Cw[rbase + j] = f2bf(acc[m][n][rr] + bv);
        }
      }
    }
    return;
  }

  #pragma unroll
  for (int n = 0; n < 4; ++n) {
    const int ccol = colL0 + n * 16 + lr;
    const float bv = ADDB ? bias[ccol] : 0.f;
    #pragma unroll
    for (int m = 0; m < 4; ++m) {
      #pragma unroll
      for (int r = 0; r < 4; ++r) {
        const int crow = row0 + m * 16 + kg * 4 + r;
        float v = acc[m][n][r] + bv;
        if (RELU) v = fmaxf(v, 0.f);
        if (OUTF32)
          ((float*)Cv)[(size_t)crow * ldC + colOff + ccol] = v;
        else
          ((unsigned short*)Cv)[(size_t)crow * ldC + colOff + ccol] = f2bf(v);
      }
    }
  }
}

// ---------------- MFMA sliding-window attention ---------------------------
// Block = (b, n, head-group of 4). Wave w handles head hg*4+w independently.
// qk: (36864, 1024) bf16 [Q | K].  vt: [b1][h][64][192] bf16.
// ctx out: row stride ldc, column offset colOff. S^T = mfma(K,Q): col=q,row=k.
__global__ __launch_bounds__(256)
void attn_mfma(const unsigned short* __restrict__ qk,
               const unsigned short* __restrict__ vt,
               unsigned short* __restrict__ ctx, int hbranch, int ldc, int colOff)
{
  __shared__ unsigned short P_lds[4][32 * 104];
  __shared__ float rinv[4][32];

  const int t = threadIdx.x;
  const int w = t >> 6, l = t & 63;
  const int lr = l & 15, kg = l >> 4;
  const int bid = blockIdx.x;
  const int hg = bid & 1;
  const int n = (bid >> 1) % 6;
  const int b = bid / 12;
  const int h = hg * 4 + w;
  const int kabase = (n - 1) * 32;

  bf16x8 qf[2][2];
  #pragma unroll
  for (int ct = 0; ct < 2; ++ct)
    #pragma unroll
    for (int ks = 0; ks < 2; ++ks)
      qf[ct][ks] = *(const bf16x8*)&qk[(size_t)(b * 192 + n * 32 + ct * 16 + lr) * 1024
                                       + h * 64 + ks * 32 + kg * 8];

  const f32x4 z4 = {0.f, 0.f, 0.f, 0.f};
  f32x4 sacc[6][2];
  #pragma unroll
  for (int mt = 0; mt < 6; ++mt) { sacc[mt][0] = z4; sacc[mt][1] = z4; }

  #pragma unroll
  for (int mt = 0; mt < 6; ++mt) {
    int ka = kabase + mt * 16 + lr;
    ka = ka < 0 ? 0 : (ka > 191 ? 191 : ka);
    const size_t row = hbranch ? (size_t)ka * 192 + b : (size_t)b * 192 + ka;
    #pragma unroll
    for (int ks = 0; ks < 2; ++ks) {
      bf16x8 kf = *(const bf16x8*)&qk[row * 1024 + 512 + h * 64 + ks * 32 + kg * 8];
      #pragma unroll
      for (int ct = 0; ct < 2; ++ct)
        sacc[mt][ct] = __builtin_amdgcn_mfma_f32_16x16x32_bf16(kf, qf[ct][ks],
                                                               sacc[mt][ct], 0, 0, 0);
    }
  }

  bf16x8 vf[4][3];
  #pragma unroll
  for (int dt = 0; dt < 4; ++dt)
    #pragma unroll
    for (int t2 = 0; t2 < 3; ++t2) {
      int ka0 = kabase + t2 * 32 + kg * 8;
      if (ka0 < 0 || ka0 > 184) ka0 = 0;
      vf[dt][t2] = *(const bf16x8*)&vt[((size_t)(b * 8 + h) * 64 + dt * 16 + lr) * 192 + ka0];
    }

  unsigned short* Pw = &P_lds[w][0];
  #pragma unroll
  for (int ct = 0; ct < 2; ++ct) {
    const int q = ct * 16 + lr;
    float mx = -1e30f;
    #pragma unroll
    for (int mt = 0; mt < 6; ++mt)
      #pragma unroll
      for (int rr = 0; rr < 4; ++rr) {
        const int kk = mt * 16 + kg * 4 + rr;
        const int ka = kabase + kk;
        const bool valid = (kk >= q) && (kk <= q + 64) && (ka >= 0) && (ka < 192);
        const float s = valid ? sacc[mt][ct][rr] : -1e30f;
        sacc[mt][ct][rr] = s;
        mx = fmaxf(mx, s);
      }
    mx = fmaxf(mx, __shfl_xor(mx, 16));
    mx = fmaxf(mx, __shfl_xor(mx, 32));
    float sum = 0.f;
    #pragma unroll
    for (int mt = 0; mt < 6; ++mt) {
      bf16x4 pk;
      #pragma unroll
      for (int rr = 0; rr < 4; ++rr) {
        const float e = exp2f((sacc[mt][ct][rr] - mx) * 0.1803368801111137f);
        sum += e;
        pk[rr] = (__bf16)e;
      }
      *(bf16x4*)&Pw[q * 104 + mt * 16 + kg * 4] = pk;
    }
    sum += __shfl_xor(sum, 16);
    sum += __shfl_xor(sum, 32);
    if (kg == 0) rinv[w][q] = 1.0f / sum;
  }

  f32x4 oacc[2][4];
  #pragma unroll
  for (int mq = 0; mq < 2; ++mq)
    #pragma unroll
    for (int dt = 0; dt < 4; ++dt) oacc[mq][dt] = z4;

  #pragma unroll
  for (int t2 = 0; t2 < 3; ++t2)
    #pragma unroll
    for (int mq = 0; mq < 2; ++mq) {
      bf16x8 pa = *(const bf16x8*)&Pw[(mq * 16 + lr) * 104 + t2 * 32 + kg * 8];
      #pragma unroll
      for (int dt = 0; dt < 4; ++dt)
        oacc[mq][dt] = __builtin_amdgcn_mfma_f32_16x16x32_bf16(pa, vf[dt][t2],
                                                               oacc[mq][dt], 0, 0, 0);
    }

  #pragma unroll
  for (int mq = 0; mq < 2; ++mq)
    #pragma unroll
    for (int rr = 0; rr < 4; ++rr) {
      const int q = mq * 16 + kg * 4 + rr;
      const float rv = rinv[w][q];
      const size_t row = (size_t)(b * 192 + n * 32 + q) * ldc + colOff + h * 64;
      #pragma unroll
      for (int dt = 0; dt < 4; ++dt)
        ctx[row + dt * 16 + lr] = f2bf(oacc[mq][dt][rr] * rv);
    }
}

// ---------------- launch ----------------
extern "C" void kernel_launch(void* const* d_in, const int* in_sizes, int n_in,
                              void* d_out, int out_size, void* d_ws, size_t ws_size,
                              hipStream_t stream) {
  const float* x       = (const float*)d_in[0];
  const float* h_in_w  = (const float*)d_in[1];
  const float* h_in_b  = (const float*)d_in[2];
  const float* h_out_w = (const float*)d_in[3];
  const float* h_out_b = (const float*)d_in[4];
  const float* v_in_w  = (const float*)d_in[5];
  const float* v_in_b  = (const float*)d_in[6];
  const float* v_out_w = (const float*)d_in[7];
  const float* v_out_b = (const float*)d_in[8];
  const float* w1      = (const float*)d_in[9];
  const float* b1      = (const float*)d_in[10];
  const float* w2      = (const float*)d_in[11];
  const float* b2      = (const float*)d_in[12];

  // workspace layout (bytes) — total unchanged: 232,259,584
  const size_t XB   = 0;                 // xb 37,748,736 (G+bf alias after QK-v)
  const size_t WVB  = 37748736;          // 1,572,864
  const size_t WHB  = 39321600;          // 1,572,864
  const size_t WHOT = 40894464;          //   524,288
  const size_t WVOT = 41418752;          //   524,288
  const size_t W1B  = 41943040;          // 1,048,576
  const size_t W2B  = 42991616;          //   524,288
  const size_t CTX2 = 43515904;          // 75,497,472 (36864 x 1024 bf16)
  const size_t QKO  = 119013376;         // 75,497,472 (xt, hid alias here)
  const size_t VTO  = 194510848;         // 37,748,736
  const size_t NEED = 232259584;
  if (ws_size < NEED) return;

  char* ws = (char*)d_ws;
  unsigned short* xb   = (unsigned short*)(ws + XB);
  unsigned short* wvb  = (unsigned short*)(ws + WVB);
  unsigned short* whb  = (unsigned short*)(ws + WHB);
  unsigned short* whoT = (unsigned short*)(ws + WHOT);
  unsigned short* wvoT = (unsigned short*)(ws + WVOT);
  unsigned short* w1b  = (unsigned short*)(ws + W1B);
  unsigned short* w2b  = (unsigned short*)(ws + W2B);
  unsigned short* ctx2 = (unsigned short*)(ws + CTX2);
  unsigned short* qko  = (unsigned short*)(ws + QKO);
  unsigned short* vto  = (unsigned short*)(ws + VTO);
  unsigned short* xt   = (unsigned short*)(ws + QKO);  // alias: consumed before QK-h
  unsigned short* hid  = (unsigned short*)(ws + QKO);  // alias: after attn-v
  unsigned short* G    = (unsigned short*)(ws + XB);   // alias: after QK-v (1 MB)
  float*          bfz  = (float*)(ws + XB + 1048576);  // fused bias (2 KB)

  // 1. converts (single kernel)
  cvt_all<<<21248, 256, 0, stream>>>(x, v_in_w, h_in_w, w1, w2, h_out_w, v_out_w,
                                     xb, xt, wvb, whb, w1b, w2b, whoT, wvoT);
  // 2-4. h branch (VT-h consumes xt before QK-h overwrites the alias)
  gemm_bt<0,0,1,1><<<192 * 8, 256, 0, stream>>>(whb + 1024 * 512, xt, vto, h_in_b + 1024,
                                                512, 192, 512, 512, 512, 192, 0);
  gemm_bt<0,0,0,1><<<288 * 8, 256, 0, stream>>>(xb, whb, qko, h_in_b,
                                                36864, 1024, 512, 512, 512, 1024, 0);
  attn_mfma<<<192 * 6 * 2, 256, 0, stream>>>(qko, vto, ctx2, 1, 1024, 0);
  // 5-7. v branch
  gemm_bt<0,0,1,1><<<192 * 8, 256, 0, stream>>>(wvb + 1024 * 512, xb, vto, v_in_b + 1024,
                                                512, 192, 512, 512, 512, 192, 0);
  gemm_bt<0,0,0,1><<<288 * 8, 256, 0, stream>>>(xb, wvb, qko, v_in_b,
                                                36864, 1024, 512, 512, 512, 1024, 0);
  attn_mfma<<<192 * 6 * 2, 256, 0, stream>>>(qko, vto, ctx2, 0, 1024, 512);
  // 8-10. fused MLP1 weight: G = [W1a.who | W1b.wvo], bias bfz
  gemm_bt<0,0,0,0><<<16, 256, 0, stream>>>(w1b, whoT, G, bfz,
                                           512, 512, 512, 1024, 512, 1024, 0);
  gemm_bt<0,0,0,0><<<16, 256, 0, stream>>>(w1b + 512, wvoT, G, bfz,
                                           512, 512, 512, 1024, 512, 1024, 512);
  fuse_bias<<<2, 256, 0, stream>>>(b1, h_out_b, v_out_b, w1, bfz);
  // 11. hid = relu(ctx2 . G^T + bfz)   (out-projections folded in)
  gemm_bt<0,1,0,1><<<288 * 4, 256, 0, stream>>>(ctx2, G, hid, bfz,
                                                36864, 512, 1024, 1024, 1024, 512, 0);
  // 12. out = hid . w2^T + b2  (fp32)
  gemm_bt<1,0,0,1><<<288 * 4, 256, 0, stream>>>(hid, w2b, d_out, b2,
                                                36864, 512, 512, 512, 512, 512, 0);
}

// Round 5
// 441.561 us; speedup vs baseline: 2.1274x; 1.0918x over previous
//
#include <hip/hip_runtime.h>

typedef __bf16 bf16x8 __attribute__((ext_vector_type(8)));
typedef __bf16 bf16x4 __attribute__((ext_vector_type(4)));
typedef float f32x4 __attribute__((ext_vector_type(4)));

__device__ __forceinline__ float bf2f(unsigned short u) {
  union { unsigned int i; float f; } v; v.i = ((unsigned int)u) << 16; return v.f;
}
__device__ __forceinline__ unsigned short f2bf(float f) {
  union { float f; unsigned int i; } v; v.f = f;
  unsigned int u = v.i;
  u += 0x7fffu + ((u >> 16) & 1u);
  return (unsigned short)(u >> 16);
}

// ---------------- fused convert: x (dual), flat weights, transposed who/wvo
__global__ void cvt_all(const float* __restrict__ x,
                        const float* __restrict__ wv, const float* __restrict__ wh,
                        const float* __restrict__ w1, const float* __restrict__ w2,
                        const float* __restrict__ who, const float* __restrict__ wvo,
                        unsigned short* __restrict__ xb, unsigned short* __restrict__ xt,
                        unsigned short* __restrict__ wvb, unsigned short* __restrict__ whb,
                        unsigned short* __restrict__ w1b, unsigned short* __restrict__ w2b,
                        unsigned short* __restrict__ whoT, unsigned short* __restrict__ wvoT)
{
  const int bid = blockIdx.x;
  const int t = threadIdx.x;
  if (bid < 18432) {
    const int ro = bid * 2 + (t >> 7);           // xt row = s*192+b
    const int idx = t & 127;
    const int s = ro / 192, b = ro - s * 192;
    const int ri = b * 192 + s;                  // x/xb row
    float4 v = *(const float4*)&x[(size_t)ri * 512 + idx * 4];
    ushort4 o;
    o.x = f2bf(v.x); o.y = f2bf(v.y); o.z = f2bf(v.z); o.w = f2bf(v.w);
    *(ushort4*)&xb[(size_t)ri * 512 + idx * 4] = o;
    *(ushort4*)&xt[(size_t)ro * 512 + idx * 4] = o;
  } else if (bid < 20736) {
    int q = (bid - 18432) * 256 + t;
    const float* src; unsigned short* dst;
    if (q < 196608)      { src = wv;  dst = wvb; }
    else if (q < 393216) { src = wh;  dst = whb; q -= 196608; }
    else if (q < 524288) { src = w1;  dst = w1b; q -= 393216; }
    else                 { src = w2;  dst = w2b; q -= 524288; }
    float4 v = ((const float4*)src)[q];
    ushort4 o;
    o.x = f2bf(v.x); o.y = f2bf(v.y); o.z = f2bf(v.z); o.w = f2bf(v.w);
    ((ushort4*)dst)[q] = o;
  } else {
    const int tb = bid - 20736;
    const float* src = (tb < 256) ? who : wvo;
    unsigned short* dst = (tb < 256) ? whoT : wvoT;
    const int j = (tb & 255) * 2 + (t >> 7);
    const int i0 = (t & 127) * 4;
    ushort4 o;
    o.x = f2bf(src[(size_t)(i0 + 0) * 512 + j]);
    o.y = f2bf(src[(size_t)(i0 + 1) * 512 + j]);
    o.z = f2bf(src[(size_t)(i0 + 2) * 512 + j]);
    o.w = f2bf(src[(size_t)(i0 + 3) * 512 + j]);
    *(ushort4*)&dst[(size_t)j * 512 + i0] = o;
  }
}

// ---------------- fused MLP1 bias: bf = b1 + W1a.h_out_b + W1b.v_out_b ----
// 16 lanes per output, 32 elems per lane per half, shuffle-reduce.
__global__ void fuse_bias(const float* __restrict__ b1,
                          const float* __restrict__ hob,
                          const float* __restrict__ vob,
                          const float* __restrict__ w1,
                          float* __restrict__ bf)
{
  const int gid = blockIdx.x * 256 + threadIdx.x;
  const int o = gid >> 4, g = gid & 15;
  if (o < 512) {
    const float* row = w1 + (size_t)o * 1024;
    float s = 0.f;
    #pragma unroll 8
    for (int m = g * 32; m < g * 32 + 32; ++m) s += row[m] * hob[m];
    #pragma unroll 8
    for (int m = g * 32; m < g * 32 + 32; ++m) s += row[512 + m] * vob[m];
    s += __shfl_xor(s, 1);
    s += __shfl_xor(s, 2);
    s += __shfl_xor(s, 4);
    s += __shfl_xor(s, 8);
    if (g == 0) bf[o] = s + b1[o];
  }
}

// ---------------- async global->LDS 16B ----------------
__device__ __forceinline__ void async16(const void* g, void* s) {
  __builtin_amdgcn_global_load_lds(
      (const __attribute__((address_space(1))) unsigned int*)g,
      (__attribute__((address_space(3))) unsigned int*)s, 16, 0, 0);
}

// ---------------- bf16 GEMM, Bt = (N,K) row-major (C = A * Bt^T) ----------
// 128x128 tile, BK=32, 4 waves (2x2), 16x16x32 MFMA.
// 3-buffer LDS pipeline, prefetch distance 2, counted vmcnt (never 0 in
// main loop), raw s_barrier (no vmcnt(0) drain). Race audit:
//   stage slot (cur+2)%3 last read at iter it-1; end barrier separates.
//   vmcnt(8) leaves tiles it+1,it+2 in flight; barrier C publishes tile it.
// MODE 0: C[M][ldC] at colOff. MODE 1: batched V^T (grid=batches*8,
//   tm=sub&3 over M=512, tn=sub>>2 covers cols tn*64..+127 of N=192;
//   middle 64 written twice, identical values). Bias by ROW in MODE 1.
template<int OUTF32, int RELU, int MODE, int ADDB>
__global__ __launch_bounds__(256, 3)
void gemm_bt(const unsigned short* __restrict__ A,
             const unsigned short* __restrict__ Bt,
             void* __restrict__ Cv,
             const float* __restrict__ bias,
             int M, int N, int K, int lda, int ldb, int ldC, int colOff)
{
  __shared__ unsigned short As[3][4096];
  __shared__ unsigned short Bs[3][4096];

  int tm, tn, batch = 0;
  if (MODE == 1) {
    batch = blockIdx.x >> 3;
    const int sub = blockIdx.x & 7;
    tm = sub & 3;
    tn = sub >> 2;
  } else {
    const int mb = M >> 7;
    tm = (int)blockIdx.x % mb;
    tn = (int)blockIdx.x / mb;
  }
  const int t = threadIdx.x;
  const int w = t >> 6, l = t & 63;
  const int wr = w >> 1, wc = w & 1;
  const int lr = l & 15, kg = l >> 4;

  const unsigned short* Abase = A + (size_t)tm * 128 * lda;
  const unsigned short* Bbase = (MODE == 1)
      ? Bt + ((size_t)batch * 192 + tn * 64) * ldb
      : Bt + (size_t)tn * 128 * ldb;

  const int r0 = t >> 2, s0 = (t & 3) * 8;
  const size_t ga0 = (size_t)r0 * lda + s0;
  const size_t ga1 = (size_t)(64 + r0) * lda + s0;
  const size_t gb0 = (size_t)r0 * ldb + s0;
  const size_t gb1 = (size_t)(64 + r0) * ldb + s0;
  const int ldsoff = w * 512;

  const f32x4 zero4 = {0.f, 0.f, 0.f, 0.f};
  f32x4 acc[4][4];
  #pragma unroll
  for (int m = 0; m < 4; ++m)
    #pragma unroll
    for (int n = 0; n < 4; ++n) acc[m][n] = zero4;

  auto stage = [&](int kt, int slot) {
    async16(Abase + ga0 + kt, &As[slot][ldsoff]);
    async16(Abase + ga1 + kt, &As[slot][2048 + ldsoff]);
    async16(Bbase + gb0 + kt, &Bs[slot][ldsoff]);
    async16(Bbase + gb1 + kt, &Bs[slot][2048 + ldsoff]);
  };

  const int nk = K >> 5;
  stage(0, 0);
  stage(32, 1);

  int cur = 0;
  for (int it = 0; it < nk; ++it) {
    int st = cur + 2; if (st >= 3) st -= 3;
    if (it + 2 < nk) {
      stage((it + 2) << 5, st);
      asm volatile("s_waitcnt vmcnt(8)" ::: "memory");   // tile it done; 8 in flight
    } else if (it + 1 < nk) {
      asm volatile("s_waitcnt vmcnt(4)" ::: "memory");
    } else {
      asm volatile("s_waitcnt vmcnt(0)" ::: "memory");
    }
    __builtin_amdgcn_sched_barrier(0);
    __builtin_amdgcn_s_barrier();          // all waves: tile it resident
    __builtin_amdgcn_sched_barrier(0);

    bf16x8 af[4], bfv[4];
    #pragma unroll
    for (int m = 0; m < 4; ++m)
      af[m] = *(const bf16x8*)&As[cur][(wr * 64 + m * 16 + lr) * 32 + kg * 8];
    #pragma unroll
    for (int n = 0; n < 4; ++n)
      bfv[n] = *(const bf16x8*)&Bs[cur][(wc * 64 + n * 16 + lr) * 32 + kg * 8];
    #pragma unroll
    for (int m = 0; m < 4; ++m)
      #pragma unroll
      for (int n = 0; n < 4; ++n)
        acc[m][n] = __builtin_amdgcn_mfma_f32_16x16x32_bf16(af[m], bfv[n],
                                                            acc[m][n], 0, 0, 0);
    __builtin_amdgcn_sched_barrier(0);
    __builtin_amdgcn_s_barrier();          // reads of slot cur done -> reusable
    cur = cur + 1; if (cur >= 3) cur = 0;
  }

  const int row0 = tm * 128 + wr * 64;
  const int colL0 = (MODE == 1) ? (tn * 64 + wc * 64) : (tn * 128 + wc * 64);

  if (MODE == 1) {
    unsigned short* Cw = (unsigned short*)Cv + (size_t)batch * 98304;
    #pragma unroll
    for (int m = 0; m < 4; ++m) {
      const int rowb = row0 + m * 16 + kg * 4;
      float4 bv4 = {0.f, 0.f, 0.f, 0.f};
      if (ADDB) bv4 = *(const float4*)&bias[rowb];
      #pragma unroll
      for (int rr = 0; rr < 4; ++rr) {
        const float bv = ((const float*)&bv4)[rr];
        const size_t rbase = (size_t)(rowb + rr) * 192;
        #pragma unroll
        for (int n = 0; n < 4; ++n) {
          const int j = colL0 + n * 16 + lr;
          Cw[rbase + j] = f2bf(acc[m][n][rr] + bv);
        }
      }
    }
    return;
  }

  #pragma unroll
  for (int n = 0; n < 4; ++n) {
    const int ccol = colL0 + n * 16 + lr;
    const float bv = ADDB ? bias[ccol] : 0.f;
    #pragma unroll
    for (int m = 0; m < 4; ++m) {
      #pragma unroll
      for (int r = 0; r < 4; ++r) {
        const int crow = row0 + m * 16 + kg * 4 + r;
        float v = acc[m][n][r] + bv;
        if (RELU) v = fmaxf(v, 0.f);
        if (OUTF32)
          ((float*)Cv)[(size_t)crow * ldC + colOff + ccol] = v;
        else
          ((unsigned short*)Cv)[(size_t)crow * ldC + colOff + ccol] = f2bf(v);
      }
    }
  }
}

// ---------------- MFMA sliding-window attention ---------------------------
// Block = (b, n, head-group of 4). Wave w handles head hg*4+w independently.
// qk: (36864, 1024) bf16 [Q | K].  vt: [b1][h][64][192] bf16.
// ctx out: row stride ldc, column offset colOff. S^T = mfma(K,Q): col=q,row=k.
__global__ __launch_bounds__(256)
void attn_mfma(const unsigned short* __restrict__ qk,
               const unsigned short* __restrict__ vt,
               unsigned short* __restrict__ ctx, int hbranch, int ldc, int colOff)
{
  __shared__ unsigned short P_lds[4][32 * 104];
  __shared__ float rinv[4][32];

  const int t = threadIdx.x;
  const int w = t >> 6, l = t & 63;
  const int lr = l & 15, kg = l >> 4;
  const int bid = blockIdx.x;
  const int hg = bid & 1;
  const int n = (bid >> 1) % 6;
  const int b = bid / 12;
  const int h = hg * 4 + w;
  const int kabase = (n - 1) * 32;

  bf16x8 qf[2][2];
  #pragma unroll
  for (int ct = 0; ct < 2; ++ct)
    #pragma unroll
    for (int ks = 0; ks < 2; ++ks)
      qf[ct][ks] = *(const bf16x8*)&qk[(size_t)(b * 192 + n * 32 + ct * 16 + lr) * 1024
                                       + h * 64 + ks * 32 + kg * 8];

  const f32x4 z4 = {0.f, 0.f, 0.f, 0.f};
  f32x4 sacc[6][2];
  #pragma unroll
  for (int mt = 0; mt < 6; ++mt) { sacc[mt][0] = z4; sacc[mt][1] = z4; }

  #pragma unroll
  for (int mt = 0; mt < 6; ++mt) {
    int ka = kabase + mt * 16 + lr;
    ka = ka < 0 ? 0 : (ka > 191 ? 191 : ka);
    const size_t row = hbranch ? (size_t)ka * 192 + b : (size_t)b * 192 + ka;
    #pragma unroll
    for (int ks = 0; ks < 2; ++ks) {
      bf16x8 kf = *(const bf16x8*)&qk[row * 1024 + 512 + h * 64 + ks * 32 + kg * 8];
      #pragma unroll
      for (int ct = 0; ct < 2; ++ct)
        sacc[mt][ct] = __builtin_amdgcn_mfma_f32_16x16x32_bf16(kf, qf[ct][ks],
                                                               sacc[mt][ct], 0, 0, 0);
    }
  }

  bf16x8 vf[4][3];
  #pragma unroll
  for (int dt = 0; dt < 4; ++dt)
    #pragma unroll
    for (int t2 = 0; t2 < 3; ++t2) {
      int ka0 = kabase + t2 * 32 + kg * 8;
      if (ka0 < 0 || ka0 > 184) ka0 = 0;
      vf[dt][t2] = *(const bf16x8*)&vt[((size_t)(b * 8 + h) * 64 + dt * 16 + lr) * 192 + ka0];
    }

  unsigned short* Pw = &P_lds[w][0];
  #pragma unroll
  for (int ct = 0; ct < 2; ++ct) {
    const int q = ct * 16 + lr;
    float mx = -1e30f;
    #pragma unroll
    for (int mt = 0; mt < 6; ++mt)
      #pragma unroll
      for (int rr = 0; rr < 4; ++rr) {
        const int kk = mt * 16 + kg * 4 + rr;
        const int ka = kabase + kk;
        const bool valid = (kk >= q) && (kk <= q + 64) && (ka >= 0) && (ka < 192);
        const float s = valid ? sacc[mt][ct][rr] : -1e30f;
        sacc[mt][ct][rr] = s;
        mx = fmaxf(mx, s);
      }
    mx = fmaxf(mx, __shfl_xor(mx, 16));
    mx = fmaxf(mx, __shfl_xor(mx, 32));
    float sum = 0.f;
    #pragma unroll
    for (int mt = 0; mt < 6; ++mt) {
      bf16x4 pk;
      #pragma unroll
      for (int rr = 0; rr < 4; ++rr) {
        const float e = exp2f((sacc[mt][ct][rr] - mx) * 0.1803368801111137f);
        sum += e;
        pk[rr] = (__bf16)e;
      }
      *(bf16x4*)&Pw[q * 104 + mt * 16 + kg * 4] = pk;
    }
    sum += __shfl_xor(sum, 16);
    sum += __shfl_xor(sum, 32);
    if (kg == 0) rinv[w][q] = 1.0f / sum;
  }

  f32x4 oacc[2][4];
  #pragma unroll
  for (int mq = 0; mq < 2; ++mq)
    #pragma unroll
    for (int dt = 0; dt < 4; ++dt) oacc[mq][dt] = z4;

  #pragma unroll
  for (int t2 = 0; t2 < 3; ++t2)
    #pragma unroll
    for (int mq = 0; mq < 2; ++mq) {
      bf16x8 pa = *(const bf16x8*)&Pw[(mq * 16 + lr) * 104 + t2 * 32 + kg * 8];
      #pragma unroll
      for (int dt = 0; dt < 4; ++dt)
        oacc[mq][dt] = __builtin_amdgcn_mfma_f32_16x16x32_bf16(pa, vf[dt][t2],
                                                               oacc[mq][dt], 0, 0, 0);
    }

  #pragma unroll
  for (int mq = 0; mq < 2; ++mq)
    #pragma unroll
    for (int rr = 0; rr < 4; ++rr) {
      const int q = mq * 16 + kg * 4 + rr;
      const float rv = rinv[w][q];
      const size_t row = (size_t)(b * 192 + n * 32 + q) * ldc + colOff + h * 64;
      #pragma unroll
      for (int dt = 0; dt < 4; ++dt)
        ctx[row + dt * 16 + lr] = f2bf(oacc[mq][dt][rr] * rv);
    }
}

// ---------------- launch ----------------
extern "C" void kernel_launch(void* const* d_in, const int* in_sizes, int n_in,
                              void* d_out, int out_size, void* d_ws, size_t ws_size,
                              hipStream_t stream) {
  const float* x       = (const float*)d_in[0];
  const float* h_in_w  = (const float*)d_in[1];
  const float* h_in_b  = (const float*)d_in[2];
  const float* h_out_w = (const float*)d_in[3];
  const float* h_out_b = (const float*)d_in[4];
  const float* v_in_w  = (const float*)d_in[5];
  const float* v_in_b  = (const float*)d_in[6];
  const float* v_out_w = (const float*)d_in[7];
  const float* v_out_b = (const float*)d_in[8];
  const float* w1      = (const float*)d_in[9];
  const float* b1      = (const float*)d_in[10];
  const float* w2      = (const float*)d_in[11];
  const float* b2      = (const float*)d_in[12];

  // workspace layout (bytes) — total: 232,259,584
  const size_t XB   = 0;                 // xb 37,748,736 (G+bf alias after QK-v)
  const size_t WVB  = 37748736;
  const size_t WHB  = 39321600;
  const size_t WHOT = 40894464;
  const size_t WVOT = 41418752;
  const size_t W1B  = 41943040;
  const size_t W2B  = 42991616;
  const size_t CTX2 = 43515904;          // 75,497,472 (36864 x 1024 bf16)
  const size_t QKO  = 119013376;         // 75,497,472 (xt, hid alias here)
  const size_t VTO  = 194510848;         // 37,748,736
  const size_t NEED = 232259584;
  if (ws_size < NEED) return;

  char* ws = (char*)d_ws;
  unsigned short* xb   = (unsigned short*)(ws + XB);
  unsigned short* wvb  = (unsigned short*)(ws + WVB);
  unsigned short* whb  = (unsigned short*)(ws + WHB);
  unsigned short* whoT = (unsigned short*)(ws + WHOT);
  unsigned short* wvoT = (unsigned short*)(ws + WVOT);
  unsigned short* w1b  = (unsigned short*)(ws + W1B);
  unsigned short* w2b  = (unsigned short*)(ws + W2B);
  unsigned short* ctx2 = (unsigned short*)(ws + CTX2);
  unsigned short* qko  = (unsigned short*)(ws + QKO);
  unsigned short* vto  = (unsigned short*)(ws + VTO);
  unsigned short* xt   = (unsigned short*)(ws + QKO);  // alias: consumed before QK-h
  unsigned short* hid  = (unsigned short*)(ws + QKO);  // alias: after attn-v
  unsigned short* G    = (unsigned short*)(ws + XB);   // alias: after QK-v (1 MB)
  float*          bfz  = (float*)(ws + XB + 1048576);  // fused bias (2 KB)

  // 1. converts (single kernel)
  cvt_all<<<21248, 256, 0, stream>>>(x, v_in_w, h_in_w, w1, w2, h_out_w, v_out_w,
                                     xb, xt, wvb, whb, w1b, w2b, whoT, wvoT);
  // 2-4. h branch (VT-h consumes xt before QK-h overwrites the alias)
  gemm_bt<0,0,1,1><<<192 * 8, 256, 0, stream>>>(whb + 1024 * 512, xt, vto, h_in_b + 1024,
                                                512, 192, 512, 512, 512, 192, 0);
  gemm_bt<0,0,0,1><<<288 * 8, 256, 0, stream>>>(xb, whb, qko, h_in_b,
                                                36864, 1024, 512, 512, 512, 1024, 0);
  attn_mfma<<<192 * 6 * 2, 256, 0, stream>>>(qko, vto, ctx2, 1, 1024, 0);
  // 5-7. v branch
  gemm_bt<0,0,1,1><<<192 * 8, 256, 0, stream>>>(wvb + 1024 * 512, xb, vto, v_in_b + 1024,
                                                512, 192, 512, 512, 512, 192, 0);
  gemm_bt<0,0,0,1><<<288 * 8, 256, 0, stream>>>(xb, wvb, qko, v_in_b,
                                                36864, 1024, 512, 512, 512, 1024, 0);
  attn_mfma<<<192 * 6 * 2, 256, 0, stream>>>(qko, vto, ctx2, 0, 1024, 512);
  // 8-10. fused MLP1 weight: G = [W1a.who | W1b.wvo], bias bfz
  gemm_bt<0,0,0,0><<<16, 256, 0, stream>>>(w1b, whoT, G, bfz,
                                           512, 512, 512, 1024, 512, 1024, 0);
  gemm_bt<0,0,0,0><<<16, 256, 0, stream>>>(w1b + 512, wvoT, G, bfz,
                                           512, 512, 512, 1024, 512, 1024, 512);
  fuse_bias<<<32, 256, 0, stream>>>(b1, h_out_b, v_out_b, w1, bfz);
  // 11. hid = relu(ctx2 . G^T + bfz)   (out-projections folded in)
  gemm_bt<0,1,0,1><<<288 * 4, 256, 0, stream>>>(ctx2, G, hid, bfz,
                                                36864, 512, 1024, 1024, 1024, 512, 0);
  // 12. out = hid . w2^T + b2  (fp32)
  gemm_bt<1,0,0,1><<<288 * 4, 256, 0, stream>>>(hid, w2b, d_out, b2,
                                                36864, 512, 512, 512, 512, 512, 0);
}